// Round 7
// baseline (286.755 us; speedup 1.0000x reference)
//
#include <hip/hip_runtime.h>
#include <hip/hip_bf16.h>
#include <math.h>

// Problem constants (fixed-shape problem)
#define NROWS 4096
#define DFEA  512
#define NCLS  751
#define DSIDE 1024
#define TAIL_BLOCKS 2560

typedef __attribute__((ext_vector_type(8))) short short8;
typedef __attribute__((ext_vector_type(4))) float f32x4;

__device__ __forceinline__ float wave_sum(float v) {
#pragma unroll
  for (int off = 32; off > 0; off >>= 1) v += __shfl_xor(v, off, 64);
  return v;
}

// async global->LDS, 16B per lane, wave-uniform LDS base + lane*16 (HW rule)
__device__ __forceinline__ void load_lds16(const void* g, void* l) {
  __builtin_amdgcn_global_load_lds((const __attribute__((address_space(1))) void*)g,
                                   (__attribute__((address_space(3))) void*)l, 16, 0, 0);
}

// branchless insert into ascending top-8 (drops the max)
__device__ __forceinline__ void ins8(float t8[8], float x) {
#pragma unroll
  for (int q = 0; q < 8; ++q) {
    const float lo = fminf(t8[q], x);
    x = fmaxf(t8[q], x);
    t8[q] = lo;
  }
}

#define CE(x, i, j) { const float ce_lo = fminf(x[i], x[j]); x[j] = fmaxf(x[i], x[j]); x[i] = ce_lo; }
#define SORT8_STAGE(c) \
  CE(c, 0, 4) CE(c, 1, 5) CE(c, 2, 6) CE(c, 3, 7) \
  CE(c, 0, 2) CE(c, 1, 3) CE(c, 4, 6) CE(c, 5, 7) \
  CE(c, 0, 1) CE(c, 2, 3) CE(c, 4, 5) CE(c, 6, 7)

// merge my ascending-8 with xor-partner's ascending-8, keep lowest 8 (sorted)
__device__ __forceinline__ void merge_sorted8(float a[8], int mask) {
  float b[8];
#pragma unroll
  for (int i = 0; i < 8; ++i) b[i] = __shfl_xor(a[i], mask, 64);
  float c[8];
#pragma unroll
  for (int i = 0; i < 8; ++i) c[i] = fminf(a[i], b[7 - i]);  // lowest-8, bitonic
  SORT8_STAGE(c)
#pragma unroll
  for (int i = 0; i < 8; ++i) a[i] = c[i];
}

// merge two local ascending-8 lists, keep lowest 8 into a (sorted)
__device__ __forceinline__ void merge8_local(float a[8], const float b[8]) {
  float c[8];
#pragma unroll
  for (int i = 0; i < 8; ++i) c[i] = fminf(a[i], b[7 - i]);
  SORT8_STAGE(c)
#pragma unroll
  for (int i = 0; i < 8; ++i) a[i] = c[i];
}

__device__ __forceinline__ unsigned short bf16bits(float v) {
  union { __hip_bfloat16 b; unsigned short u; } cv;
  cv.b = __float2bfloat16(v);
  return cv.u;
}

// ---------------- fused: row sum-of-squares + top1 accuracy + bf16 split + slot zeroing ----------------
__global__ __launch_bounds__(256) void k_prep(const float* __restrict__ fea,
                                              const int* __restrict__ tgt,
                                              float* __restrict__ sq,
                                              float* __restrict__ pa,
                                              unsigned short* __restrict__ Fhi,
                                              unsigned short* __restrict__ Flo,
                                              float* __restrict__ slots) {
  // zero 6*64 slots + completion counter (strided: block has only 256 threads!)
  if (blockIdx.x == 0) {
    for (int i = threadIdx.x; i < 385; i += 256) slots[i] = 0.0f;
  }
  const int lane = threadIdx.x & 63;
  const int wid  = threadIdx.x >> 6;
  const int row  = blockIdx.x * 4 + wid;
  const float4* xr = (const float4*)(fea + (size_t)row * DFEA);
  ushort4* hr = (ushort4*)(Fhi + (size_t)row * DFEA);
  ushort4* lr = (ushort4*)(Flo + (size_t)row * DFEA);
  float s = 0.0f, bv = -1e30f;
  int bi = 0;
#pragma unroll
  for (int q = 0; q < 2; ++q) {
    const int i4 = q * 64 + lane;
    const float4 v = xr[i4];
    s += v.x * v.x + v.y * v.y + v.z * v.z + v.w * v.w;
    const int c0 = i4 * 4;
    if (v.x > bv) { bv = v.x; bi = c0; }
    if (v.y > bv) { bv = v.y; bi = c0 + 1; }
    if (v.z > bv) { bv = v.z; bi = c0 + 2; }
    if (v.w > bv) { bv = v.w; bi = c0 + 3; }
    ushort4 h, l;
    float hf;
    h.x = bf16bits(v.x); hf = __bfloat162float(__ushort_as_bfloat16(h.x)); l.x = bf16bits(v.x - hf);
    h.y = bf16bits(v.y); hf = __bfloat162float(__ushort_as_bfloat16(h.y)); l.y = bf16bits(v.y - hf);
    h.z = bf16bits(v.z); hf = __bfloat162float(__ushort_as_bfloat16(h.z)); l.z = bf16bits(v.z - hf);
    h.w = bf16bits(v.w); hf = __bfloat162float(__ushort_as_bfloat16(h.w)); l.w = bf16bits(v.w - hf);
    hr[i4] = h;
    lr[i4] = l;
  }
#pragma unroll
  for (int off = 32; off > 0; off >>= 1) {
    s += __shfl_xor(s, off, 64);
    const float ov = __shfl_xor(bv, off, 64);
    const int   oi = __shfl_xor(bi, off, 64);
    if (ov > bv || (ov == bv && oi < bi)) { bv = ov; bi = oi; }  // first-index on tie
  }
  __shared__ float red[4];
  if (lane == 0) {
    sq[row]  = s;
    red[wid] = (bi == tgt[row]) ? 1.0f : 0.0f;
  }
  __syncthreads();
  if (threadIdx.x == 0) pa[blockIdx.x] = red[0] + red[1] + red[2] + red[3];
}

// ---------------- symmetric MFMA distance GEMM + two-way top-8 mining ----------------
// Compact triangular grid: 528 blocks cover (by, bx) with bx >= by (32x32 tile grid).
// 128x128 tile, BK=64, 512 threads = 8 waves (2 row x 4 col), per-wave 64x32 (acc[4][2]).
// Off-diag blocks mine rows (-> part[row][bx]) AND cols (-> part[col][by]).
__global__ __launch_bounds__(512, 4) void k_gemm_mfma(const unsigned short* __restrict__ Fhi,
                                                      const unsigned short* __restrict__ Flo,
                                                      const float* __restrict__ sq,
                                                      float* __restrict__ posw,
                                                      float* __restrict__ part) {
  const int bid = blockIdx.x;
  int by = (int)((65.0f - sqrtf(4225.0f - 8.0f * (float)bid)) * 0.5f);
  while ((by + 1) * (65 - (by + 1)) / 2 <= bid) ++by;   // fixup float decode
  while (by * (65 - by) / 2 > bid) --by;
  const int bx = by + (bid - by * (65 - by) / 2);

  const int R0 = by * 128, C0 = bx * 128;
  const int tid = threadIdx.x;
  const int lane = tid & 63, wid = tid >> 6;
  const int wr = wid >> 2, wc = wid & 3;       // 2 x 4 wave grid
  const int l15 = lane & 15, l4 = lane >> 4;

  __shared__ __attribute__((aligned(16))) char smem[37376];
  const __hip_bfloat16 (*As)[64] = (const __hip_bfloat16(*)[64])smem;           // 128x64, 16KB
  const __hip_bfloat16 (*Bs)[64] = (const __hip_bfloat16(*)[64])(smem + 16384); // 128x64, 16KB
  float (*dtile)[130] = (float(*)[130])smem;   // 64x130 f32 (33280B), aliased post-GEMM
  float* colb = (float*)(smem + 33280);        // 128x8 col-mine partials (4KB), NOT aliased

  f32x4 acc[4][2];
#pragma unroll
  for (int m = 0; m < 4; ++m)
#pragma unroll
    for (int n = 0; n < 2; ++n) acc[m][n] = (f32x4){0.0f, 0.0f, 0.0f, 0.0f};

  for (int kt = 0; kt < 24; ++kt) {
    // K-segments: kt 0..7: A=hi,B=hi | 8..15: A=hi,B=lo | 16..23: A=lo,B=hi
    const unsigned short* Aseg = (kt < 16) ? Fhi : Flo;
    const unsigned short* Bseg = (kt >= 8 && kt < 16) ? Flo : Fhi;
    const int ks = (kt & 7) * 64;
    __syncthreads();  // previous iteration's ds_reads done before overwrite
#pragma unroll
    for (int i = 0; i < 2; ++i) {
      const int flat = i * 512 + tid;
      const int row = flat >> 3, c8 = flat & 7;
      load_lds16(Aseg + (size_t)(R0 + row) * DFEA + ks + c8 * 8,
                 smem + (i * 512 + wid * 64) * 16);
      load_lds16(Bseg + (size_t)(C0 + row) * DFEA + ks + c8 * 8,
                 smem + 16384 + (i * 512 + wid * 64) * 16);
    }
    __syncthreads();  // vmcnt(0) drain + barrier (compiler-inserted)
#pragma unroll
    for (int kk = 0; kk < 2; ++kk) {
      short8 af[4], bf[2];
#pragma unroll
      for (int m = 0; m < 4; ++m)
        af[m] = *(const short8*)&As[wr * 64 + m * 16 + l15][kk * 32 + l4 * 8];
#pragma unroll
      for (int n = 0; n < 2; ++n)
        bf[n] = *(const short8*)&Bs[wc * 32 + n * 16 + l15][kk * 32 + l4 * 8];
#pragma unroll
      for (int m = 0; m < 4; ++m)
#pragma unroll
        for (int n = 0; n < 2; ++n)
          acc[m][n] = __builtin_amdgcn_mfma_f32_16x16x32_bf16(af[m], bf[n], acc[m][n], 0, 0, 0);
    }
  }

  // epilogue: d2 = sq_i + sq_j - 2*dot; row mining (+ col mining off-diag)
  float sqi[4][4], sqj[2];
#pragma unroll
  for (int m = 0; m < 4; ++m)
#pragma unroll
    for (int r = 0; r < 4; ++r) sqi[m][r] = sq[R0 + wr * 64 + m * 16 + l4 * 4 + r];
#pragma unroll
  for (int n = 0; n < 2; ++n) sqj[n] = sq[C0 + wc * 32 + n * 16 + l15];

  const bool diag = (bx == by);

  for (int h = 0; h < 2; ++h) {  // two 64-row halves share the dtile
    __syncthreads();             // prior phase's LDS reads done
    if (wr == h) {
      // C/D layout (verified m89/m91): col = lane&15, row = (lane>>4)*4 + reg
#pragma unroll
      for (int m = 0; m < 4; ++m)
#pragma unroll
        for (int n = 0; n < 2; ++n)
#pragma unroll
          for (int r = 0; r < 4; ++r)
            dtile[m * 16 + l4 * 4 + r][wc * 32 + n * 16 + l15] =
                sqi[m][r] + sqj[n] - 2.0f * acc[m][n][r];
    }
    __syncthreads();
    // row mining: 8 threads per row, 16 cols each (rotated to spread banks)
    {
      const int r = tid >> 3, q = tid & 7;
      const int rg = R0 + h * 64 + r;
      float t8[8];
#pragma unroll
      for (int i = 0; i < 8; ++i) t8[i] = 1e30f;
      if (diag) {
        for (int s = 0; s < 16; ++s) {
          const int cl = q * 16 + ((s + 3 * q) & 15);
          const int cg = C0 + cl;
          const float v = dtile[r][cl];
          if (((rg ^ cg) >> 3) == 0) posw[(size_t)rg * 8 + (cg & 7)] = v;  // same identity
          else if (v < t8[7]) ins8(t8, v);
        }
      } else {
        for (int s = 0; s < 16; ++s) {
          const float v = dtile[r][q * 16 + ((s + 3 * q) & 15)];
          if (v < t8[7]) ins8(t8, v);
        }
      }
      merge_sorted8(t8, 1);
      merge_sorted8(t8, 2);
      merge_sorted8(t8, 4);
      if (q == 0) {
        const float4 o0 = {t8[0], t8[1], t8[2], t8[3]};
        const float4 o1 = {t8[4], t8[5], t8[6], t8[7]};
        *(float4*)&part[(size_t)rg * 256 + bx * 8] = o0;
        *(float4*)&part[(size_t)rg * 256 + bx * 8 + 4] = o1;
      }
    }
    // col mining (off-diag only): 4 threads per col, 16 rows each
    if (!diag) {
      const int c = tid >> 2, sub = tid & 3;
      float c8[8];
#pragma unroll
      for (int i = 0; i < 8; ++i) c8[i] = 1e30f;
      for (int s = 0; s < 16; ++s) {
        const float v = dtile[sub * 16 + ((s + 5 * sub) & 15)][c];
        if (v < c8[7]) ins8(c8, v);
      }
      merge_sorted8(c8, 1);
      merge_sorted8(c8, 2);
      if (sub == 0) {
        if (h == 0) {
#pragma unroll
          for (int i = 0; i < 8; ++i) colb[c * 8 + i] = c8[i];
        } else {
          float o8[8];
#pragma unroll
          for (int i = 0; i < 8; ++i) o8[i] = colb[c * 8 + i];
          merge8_local(c8, o8);
          const int cg = C0 + c;
          const float4 o0 = {c8[0], c8[1], c8[2], c8[3]};
          const float4 o1 = {c8[4], c8[5], c8[6], c8[7]};
          *(float4*)&part[(size_t)cg * 256 + by * 8] = o0;
          *(float4*)&part[(size_t)cg * 256 + by * 8 + 4] = o1;
        }
      }
    }
  }
}

// ---------------- fused tail: rank-loss merge + xent + side + last-block finalize ----------------
// blocks [0,1024): rank loss (4 rows each) + accuracy partial
// blocks [1024,2048): cross entropy (4 rows each)
// blocks [2048,2560): side losses (grid-stride)
// last block to finish reduces the 6x64 slot array and writes out[0..1].
__global__ __launch_bounds__(256) void k_tail(const float* __restrict__ part,
                                              const float* __restrict__ posw,
                                              const float* __restrict__ pa,
                                              const float* __restrict__ cls,
                                              const int* __restrict__ tgt,
                                              const float* __restrict__ l2,
                                              const float* __restrict__ l3,
                                              const float* __restrict__ l4,
                                              float* __restrict__ slots,
                                              int* __restrict__ counter,
                                              float* __restrict__ out) {
  const int bid = blockIdx.x, tid = threadIdx.x;
  const int lane = tid & 63, w = tid >> 6;
  __shared__ float red[8];
  __shared__ float qs[6];
  __shared__ int islast;

  if (bid < 1024) {
    // ---- rank loss: one wave per row ----
    const int row = bid * 4 + w;
    float a[8];
    if (lane < 32) {
      const float4 v0 = *(const float4*)&part[(size_t)row * 256 + lane * 8];
      const float4 v1 = *(const float4*)&part[(size_t)row * 256 + lane * 8 + 4];
      a[0] = v0.x; a[1] = v0.y; a[2] = v0.z; a[3] = v0.w;
      a[4] = v1.x; a[5] = v1.y; a[6] = v1.z; a[7] = v1.w;
    } else {
#pragma unroll
      for (int i = 0; i < 8; ++i) a[i] = 1e30f;
    }
    merge_sorted8(a, 1);
    merge_sorted8(a, 2);
    merge_sorted8(a, 4);
    merge_sorted8(a, 8);
    merge_sorted8(a, 16);  // lanes 0..31 hold global top-8 (ascending d2)
    if (lane == 0) {
      float nd[8];
#pragma unroll
      for (int i = 0; i < 8; ++i) nd[i] = sqrtf(fmaxf(a[i], 1e-12f));
      float s8[8];
#pragma unroll
      for (int i = 0; i < 8; ++i) s8[i] = 1e30f;
#pragma unroll
      for (int i = 0; i < 8; ++i)
        ins8(s8, sqrtf(fmaxf(posw[(size_t)row * 8 + i], 1e-12f)));  // positives ascending
      int ip = 0, in_ = 0;
#pragma unroll
      for (int s = 0; s < 8; ++s) {  // m = #negatives among 8 smallest of union
        const bool takeNeg = (in_ < 8) && (ip >= 8 || nd[in_] < s8[ip]);
        if (takeNeg) ++in_; else ++ip;
      }
      const int m = in_;
      float loss = 0.0f;
      const float n0 = nd[0];
      for (int k = 0; k < m; ++k)
        loss += (float)(m - k) * expf((n0 - nd[k]) / (n0 + 1e-12f)) * (s8[7 - k] - nd[k]) + 0.5f;
      red[w] = loss;
      red[4 + w] = (m == 0) ? 1.0f : 0.0f;
    }
  } else if (bid < 2048) {
    // ---- cross entropy: one wave per row ----
    const int row = (bid - 1024) * 4 + w;
    const float* x = cls + (size_t)row * NCLS;
    float mx = -1e30f;
    for (int c = lane; c < NCLS; c += 64) mx = fmaxf(mx, x[c]);
#pragma unroll
    for (int off = 32; off > 0; off >>= 1) mx = fmaxf(mx, __shfl_xor(mx, off, 64));
    float se = 0.0f;
    for (int c = lane; c < NCLS; c += 64) se += expf(x[c] - mx);
    se = wave_sum(se);
    if (lane == 0) red[w] = logf(se) + mx - x[tgt[row]];
  } else {
    // ---- side losses: grid-stride over 1M float4 ----
    float s2 = 0.0f, s3 = 0.0f;
    for (int i = (bid - 2048) * 256 + tid; i < (NROWS * DSIDE / 4); i += 512 * 256) {
      const float4 a2 = ((const float4*)l2)[i];
      const float4 a3 = ((const float4*)l3)[i];
      const float4 a4 = ((const float4*)l4)[i];
      float dx = a4.x - a2.x, dy = a4.y - a2.y, dz = a4.z - a2.z, dw = a4.w - a2.w;
      s2 += dx * dx + dy * dy + dz * dz + dw * dw;
      dx = a4.x - a3.x; dy = a4.y - a3.y; dz = a4.z - a3.z; dw = a4.w - a3.w;
      s3 += dx * dx + dy * dy + dz * dz + dw * dw;
    }
    s2 = wave_sum(s2);
    s3 = wave_sum(s3);
    if (lane == 0) { red[w] = s2; red[4 + w] = s3; }
  }
  __syncthreads();

  if (tid == 0) {
    const int sl = bid & 63;
    if (bid < 1024) {
      atomicAdd(&slots[0 * 64 + sl], red[0] + red[1] + red[2] + red[3]);
      atomicAdd(&slots[1 * 64 + sl], red[4] + red[5] + red[6] + red[7]);
      atomicAdd(&slots[3 * 64 + sl], pa[bid]);
    } else if (bid < 2048) {
      atomicAdd(&slots[2 * 64 + sl], red[0] + red[1] + red[2] + red[3]);
    } else {
      atomicAdd(&slots[4 * 64 + sl], red[0] + red[1] + red[2] + red[3]);
      atomicAdd(&slots[5 * 64 + sl], red[4] + red[5] + red[6] + red[7]);
    }
    __threadfence();
    const int old = atomicAdd(counter, 1);
    islast = (old == TAIL_BLOCKS - 1) ? 1 : 0;
  }
  __syncthreads();

  if (islast) {
    // device-coherent reads via atomicAdd(p, 0): quantities 0..3 by waves 0..3,
    // quantities 4..5 by waves 0..1 (second read)
    float a0 = atomicAdd(&slots[tid], 0.0f);
    float a1 = (tid < 128) ? atomicAdd(&slots[256 + tid], 0.0f) : 0.0f;
    a0 = wave_sum(a0);
    a1 = wave_sum(a1);
    if (lane == 0) {
      qs[w] = a0;
      if (w < 2) qs[4 + w] = a1;
    }
    __syncthreads();
    if (tid == 0) {
      const float rank_loss = qs[0] / (float)NROWS;
      const float prec      = qs[1] / (float)NROWS;
      const float xent      = qs[2] / (float)NROWS;
      const float acc       = qs[3] / (float)NROWS;
      const float side      = sqrtf(qs[4]) + sqrtf(qs[5]);
      out[0] = rank_loss + xent + 0.1f * side;  // ALPHA=GAMMA=1, THETA=0.1
      out[1] = fmaxf(prec, acc);
    }
  }
}

extern "C" void kernel_launch(void* const* d_in, const int* in_sizes, int n_in,
                              void* d_out, int out_size, void* d_ws, size_t ws_size,
                              hipStream_t stream) {
  (void)in_sizes; (void)n_in; (void)out_size; (void)ws_size;
  const float* cls = (const float*)d_in[0];
  const float* l2  = (const float*)d_in[1];
  const float* l3  = (const float*)d_in[2];
  const float* l4  = (const float*)d_in[3];
  const float* fea = (const float*)d_in[4];
  const int*   tgt = (const int*)d_in[5];
  float* out = (float*)d_out;

  // ws layout (floats): sq[4096] | Fhi (1M) | Flo (1M) | part (1M) | posw (32K)
  //                     | pa[1024] | slots[384] + counter[1]
  float* sq   = (float*)d_ws;
  unsigned short* Fhi = (unsigned short*)(sq + NROWS);
  unsigned short* Flo = Fhi + (size_t)NROWS * DFEA;
  float* part = (float*)(Flo + (size_t)NROWS * DFEA);
  float* posw = part + (size_t)NROWS * 256;
  float* pa   = posw + (size_t)NROWS * 8;
  float* slots = pa + 1024;
  int* counter = (int*)(slots + 384);

  k_prep<<<dim3(NROWS / 4), dim3(256), 0, stream>>>(fea, tgt, sq, pa, Fhi, Flo, slots);
  k_gemm_mfma<<<dim3(528), dim3(512), 0, stream>>>(Fhi, Flo, sq, posw, part);
  k_tail<<<dim3(TAIL_BLOCKS), dim3(256), 0, stream>>>(part, posw, pa, cls, tgt, l2, l3, l4,
                                                      slots, counter, out);
}

// Round 8
// 222.613 us; speedup vs baseline: 1.2881x; 1.2881x over previous
//
#include <hip/hip_runtime.h>
#include <hip/hip_bf16.h>
#include <math.h>

// Problem constants (fixed-shape problem)
#define NROWS 4096
#define DFEA  512
#define NCLS  751
#define DSIDE 1024

typedef __attribute__((ext_vector_type(8))) short short8;
typedef __attribute__((ext_vector_type(4))) float f32x4;

__device__ __forceinline__ float wave_sum(float v) {
#pragma unroll
  for (int off = 32; off > 0; off >>= 1) v += __shfl_xor(v, off, 64);
  return v;
}

// async global->LDS, 16B per lane, wave-uniform LDS base + lane*16 (HW rule)
__device__ __forceinline__ void load_lds16(const void* g, void* l) {
  __builtin_amdgcn_global_load_lds((const __attribute__((address_space(1))) void*)g,
                                   (__attribute__((address_space(3))) void*)l, 16, 0, 0);
}

// branchless insert into ascending top-8 (drops the max)
__device__ __forceinline__ void ins8(float t8[8], float x) {
#pragma unroll
  for (int q = 0; q < 8; ++q) {
    const float lo = fminf(t8[q], x);
    x = fmaxf(t8[q], x);
    t8[q] = lo;
  }
}

#define CE(x, i, j) { const float ce_lo = fminf(x[i], x[j]); x[j] = fmaxf(x[i], x[j]); x[i] = ce_lo; }
#define SORT8_STAGE(c) \
  CE(c, 0, 4) CE(c, 1, 5) CE(c, 2, 6) CE(c, 3, 7) \
  CE(c, 0, 2) CE(c, 1, 3) CE(c, 4, 6) CE(c, 5, 7) \
  CE(c, 0, 1) CE(c, 2, 3) CE(c, 4, 5) CE(c, 6, 7)

// merge my ascending-8 with xor-partner's ascending-8, keep lowest 8 (sorted)
__device__ __forceinline__ void merge_sorted8(float a[8], int mask) {
  float b[8];
#pragma unroll
  for (int i = 0; i < 8; ++i) b[i] = __shfl_xor(a[i], mask, 64);
  float c[8];
#pragma unroll
  for (int i = 0; i < 8; ++i) c[i] = fminf(a[i], b[7 - i]);  // lowest-8, bitonic
  SORT8_STAGE(c)
#pragma unroll
  for (int i = 0; i < 8; ++i) a[i] = c[i];
}

// merge two local ascending-8 lists, keep lowest 8 into a (sorted)
__device__ __forceinline__ void merge8_local(float a[8], const float b[8]) {
  float c[8];
#pragma unroll
  for (int i = 0; i < 8; ++i) c[i] = fminf(a[i], b[7 - i]);
  SORT8_STAGE(c)
#pragma unroll
  for (int i = 0; i < 8; ++i) a[i] = c[i];
}

__device__ __forceinline__ unsigned short bf16bits(float v) {
  union { __hip_bfloat16 b; unsigned short u; } cv;
  cv.b = __float2bfloat16(v);
  return cv.u;
}

// ---------------- fused: row sum-of-squares + top1 accuracy + bf16 split ----------------
__global__ __launch_bounds__(256) void k_prep(const float* __restrict__ fea,
                                              const int* __restrict__ tgt,
                                              float* __restrict__ sq,
                                              float* __restrict__ pa,
                                              unsigned short* __restrict__ Fhi,
                                              unsigned short* __restrict__ Flo) {
  const int lane = threadIdx.x & 63;
  const int wid  = threadIdx.x >> 6;
  const int row  = blockIdx.x * 4 + wid;
  const float4* xr = (const float4*)(fea + (size_t)row * DFEA);
  ushort4* hr = (ushort4*)(Fhi + (size_t)row * DFEA);
  ushort4* lr = (ushort4*)(Flo + (size_t)row * DFEA);
  float s = 0.0f, bv = -1e30f;
  int bi = 0;
#pragma unroll
  for (int q = 0; q < 2; ++q) {
    const int i4 = q * 64 + lane;
    const float4 v = xr[i4];
    s += v.x * v.x + v.y * v.y + v.z * v.z + v.w * v.w;
    const int c0 = i4 * 4;
    if (v.x > bv) { bv = v.x; bi = c0; }
    if (v.y > bv) { bv = v.y; bi = c0 + 1; }
    if (v.z > bv) { bv = v.z; bi = c0 + 2; }
    if (v.w > bv) { bv = v.w; bi = c0 + 3; }
    ushort4 h, l;
    float hf;
    h.x = bf16bits(v.x); hf = __bfloat162float(__ushort_as_bfloat16(h.x)); l.x = bf16bits(v.x - hf);
    h.y = bf16bits(v.y); hf = __bfloat162float(__ushort_as_bfloat16(h.y)); l.y = bf16bits(v.y - hf);
    h.z = bf16bits(v.z); hf = __bfloat162float(__ushort_as_bfloat16(h.z)); l.z = bf16bits(v.z - hf);
    h.w = bf16bits(v.w); hf = __bfloat162float(__ushort_as_bfloat16(h.w)); l.w = bf16bits(v.w - hf);
    hr[i4] = h;
    lr[i4] = l;
  }
#pragma unroll
  for (int off = 32; off > 0; off >>= 1) {
    s += __shfl_xor(s, off, 64);
    const float ov = __shfl_xor(bv, off, 64);
    const int   oi = __shfl_xor(bi, off, 64);
    if (ov > bv || (ov == bv && oi < bi)) { bv = ov; bi = oi; }  // first-index on tie
  }
  __shared__ float red[4];
  if (lane == 0) {
    sq[row]  = s;
    red[wid] = (bi == tgt[row]) ? 1.0f : 0.0f;
  }
  __syncthreads();
  if (threadIdx.x == 0) pa[blockIdx.x] = red[0] + red[1] + red[2] + red[3];
}

// ---------------- symmetric MFMA distance GEMM + two-way top-8 mining ----------------
// Triangular grid: 528 blocks cover (by, bx) with bx >= by (32x32 tile grid).
// R3-proven inner structure: 128x128 tile, BK=64, 256 threads = 4 waves (2x2),
// per-wave 64x64 output (acc[4][4]). Off-diag blocks mine rows (-> part[row][bx])
// AND cols (-> part[col][by], via colb LDS buffer across the two halves).
__global__ __launch_bounds__(256) void k_gemm_mfma(const unsigned short* __restrict__ Fhi,
                                                   const unsigned short* __restrict__ Flo,
                                                   const float* __restrict__ sq,
                                                   float* __restrict__ posw,
                                                   float* __restrict__ part) {
  const int bid = blockIdx.x;
  int by = (int)((65.0f - sqrtf(4225.0f - 8.0f * (float)bid)) * 0.5f);
  while ((by + 1) * (65 - (by + 1)) / 2 <= bid) ++by;   // fixup float decode
  while (by * (65 - by) / 2 > bid) --by;
  const int bx = by + (bid - by * (65 - by) / 2);

  const int R0 = by * 128, C0 = bx * 128;
  const int tid = threadIdx.x;
  const int lane = tid & 63, wid = tid >> 6;
  const int wr = wid >> 1, wc = wid & 1;
  const int l15 = lane & 15, l4 = lane >> 4;

  __shared__ __attribute__((aligned(16))) char smem[37376];
  const __hip_bfloat16 (*As)[64] = (const __hip_bfloat16(*)[64])smem;           // 128x64, 16KB
  const __hip_bfloat16 (*Bs)[64] = (const __hip_bfloat16(*)[64])(smem + 16384); // 128x64, 16KB
  float (*dtile)[130] = (float(*)[130])smem;   // 64x130 f32 (33280B), aliased post-GEMM
  float* colb = (float*)(smem + 33280);        // 128x8 col-mine partials (4KB), NOT aliased

  f32x4 acc[4][4];
#pragma unroll
  for (int m = 0; m < 4; ++m)
#pragma unroll
    for (int n = 0; n < 4; ++n) acc[m][n] = (f32x4){0.0f, 0.0f, 0.0f, 0.0f};

  for (int kt = 0; kt < 24; ++kt) {
    // K-segments: kt 0..7: A=hi,B=hi | 8..15: A=hi,B=lo | 16..23: A=lo,B=hi
    const unsigned short* Aseg = (kt < 16) ? Fhi : Flo;
    const unsigned short* Bseg = (kt >= 8 && kt < 16) ? Flo : Fhi;
    const int ks = (kt & 7) * 64;
    __syncthreads();  // previous iteration's ds_reads done before overwrite
#pragma unroll
    for (int i = 0; i < 4; ++i) {
      const int flat = i * 256 + tid;
      const int row = flat >> 3, c8 = flat & 7;
      load_lds16(Aseg + (size_t)(R0 + row) * DFEA + ks + c8 * 8,
                 smem + (i * 256 + wid * 64) * 16);
      load_lds16(Bseg + (size_t)(C0 + row) * DFEA + ks + c8 * 8,
                 smem + 16384 + (i * 256 + wid * 64) * 16);
    }
    __syncthreads();  // vmcnt(0) drain + barrier (compiler-inserted)
#pragma unroll
    for (int kk = 0; kk < 2; ++kk) {
      short8 af[4], bf[4];
#pragma unroll
      for (int m = 0; m < 4; ++m)
        af[m] = *(const short8*)&As[wr * 64 + m * 16 + l15][kk * 32 + l4 * 8];
#pragma unroll
      for (int n = 0; n < 4; ++n)
        bf[n] = *(const short8*)&Bs[wc * 64 + n * 16 + l15][kk * 32 + l4 * 8];
#pragma unroll
      for (int m = 0; m < 4; ++m)
#pragma unroll
        for (int n = 0; n < 4; ++n)
          acc[m][n] = __builtin_amdgcn_mfma_f32_16x16x32_bf16(af[m], bf[n], acc[m][n], 0, 0, 0);
    }
  }

  // epilogue: d2 = sq_i + sq_j - 2*dot; row mining (+ col mining off-diag)
  float sqi[4][4], sqj[4];
#pragma unroll
  for (int m = 0; m < 4; ++m)
#pragma unroll
    for (int r = 0; r < 4; ++r) sqi[m][r] = sq[R0 + wr * 64 + m * 16 + l4 * 4 + r];
#pragma unroll
  for (int n = 0; n < 4; ++n) sqj[n] = sq[C0 + wc * 64 + n * 16 + l15];

  const bool diag = (bx == by);

  for (int h = 0; h < 2; ++h) {  // two 64-row halves share the dtile
    __syncthreads();             // prior phase's LDS reads done
    if (wr == h) {
      // C/D layout (verified m89/m91): col = lane&15, row = (lane>>4)*4 + reg
#pragma unroll
      for (int m = 0; m < 4; ++m)
#pragma unroll
        for (int n = 0; n < 4; ++n)
#pragma unroll
          for (int r = 0; r < 4; ++r)
            dtile[m * 16 + l4 * 4 + r][wc * 64 + n * 16 + l15] =
                sqi[m][r] + sqj[n] - 2.0f * acc[m][n][r];
    }
    __syncthreads();
    // row mining: 4 threads per row, 32 cols each (rotated to spread banks)
    {
      const int r = tid >> 2, q = tid & 3;
      const int rg = R0 + h * 64 + r;
      float t8[8];
#pragma unroll
      for (int i = 0; i < 8; ++i) t8[i] = 1e30f;
      if (diag) {
        for (int s = 0; s < 32; ++s) {
          const int cl = q * 32 + ((s + 9 * q) & 31);
          const int cg = C0 + cl;
          const float v = dtile[r][cl];
          if (((rg ^ cg) >> 3) == 0) posw[(size_t)rg * 8 + (cg & 7)] = v;  // same identity
          else if (v < t8[7]) ins8(t8, v);
        }
      } else {
        for (int s = 0; s < 32; ++s) {
          const float v = dtile[r][q * 32 + ((s + 9 * q) & 31)];
          if (v < t8[7]) ins8(t8, v);
        }
      }
      merge_sorted8(t8, 1);
      merge_sorted8(t8, 2);
      if (q == 0) {
        const float4 o0 = {t8[0], t8[1], t8[2], t8[3]};
        const float4 o1 = {t8[4], t8[5], t8[6], t8[7]};
        *(float4*)&part[(size_t)rg * 256 + bx * 8] = o0;
        *(float4*)&part[(size_t)rg * 256 + bx * 8 + 4] = o1;
      }
    }
    // col mining (off-diag only): 2 threads per col, 32 rows each (2-way alias, free)
    if (!diag) {
      const int c = tid >> 1, q2 = tid & 1;
      float c8[8];
#pragma unroll
      for (int i = 0; i < 8; ++i) c8[i] = 1e30f;
      for (int s = 0; s < 32; ++s) {
        const float v = dtile[q2 * 32 + s][c];
        if (v < c8[7]) ins8(c8, v);
      }
      merge_sorted8(c8, 1);  // partner = same col, other 32-row half
      if (q2 == 0) {
        if (h == 0) {
#pragma unroll
          for (int i = 0; i < 8; ++i) colb[c * 8 + i] = c8[i];
        } else {
          float o8[8];
#pragma unroll
          for (int i = 0; i < 8; ++i) o8[i] = colb[c * 8 + i];
          merge8_local(c8, o8);
          const int cg = C0 + c;
          const float4 o0 = {c8[0], c8[1], c8[2], c8[3]};
          const float4 o1 = {c8[4], c8[5], c8[6], c8[7]};
          *(float4*)&part[(size_t)cg * 256 + by * 8] = o0;
          *(float4*)&part[(size_t)cg * 256 + by * 8 + 4] = o1;
        }
      }
    }
  }
}

// ---------------- rank loss: merge 32 sorted-8 partials per row + loss ----------------
__global__ __launch_bounds__(256) void k_rank(const float* __restrict__ part,
                                              const float* __restrict__ posw,
                                              float* __restrict__ pl,
                                              float* __restrict__ pc) {
  const int lane = threadIdx.x & 63, w = threadIdx.x >> 6;
  const int row = blockIdx.x * 4 + w;
  float a[8];
  if (lane < 32) {
    const float4 v0 = *(const float4*)&part[(size_t)row * 256 + lane * 8];
    const float4 v1 = *(const float4*)&part[(size_t)row * 256 + lane * 8 + 4];
    a[0] = v0.x; a[1] = v0.y; a[2] = v0.z; a[3] = v0.w;
    a[4] = v1.x; a[5] = v1.y; a[6] = v1.z; a[7] = v1.w;
  } else {
#pragma unroll
    for (int i = 0; i < 8; ++i) a[i] = 1e30f;
  }
  merge_sorted8(a, 1);
  merge_sorted8(a, 2);
  merge_sorted8(a, 4);
  merge_sorted8(a, 8);
  merge_sorted8(a, 16);  // lanes 0..31 hold global top-8 (ascending d2)
  __shared__ float red[8];
  if (lane == 0) {
    float nd[8];
#pragma unroll
    for (int i = 0; i < 8; ++i) nd[i] = sqrtf(fmaxf(a[i], 1e-12f));
    float s8[8];
#pragma unroll
    for (int i = 0; i < 8; ++i) s8[i] = 1e30f;
#pragma unroll
    for (int i = 0; i < 8; ++i)
      ins8(s8, sqrtf(fmaxf(posw[(size_t)row * 8 + i], 1e-12f)));  // positives ascending
    int ip = 0, in_ = 0;
#pragma unroll
    for (int s = 0; s < 8; ++s) {  // m = #negatives among 8 smallest of union
      const bool takeNeg = (in_ < 8) && (ip >= 8 || nd[in_] < s8[ip]);
      if (takeNeg) ++in_; else ++ip;
    }
    const int m = in_;
    float loss = 0.0f;
    const float n0 = nd[0];
    for (int k = 0; k < m; ++k)
      loss += (float)(m - k) * expf((n0 - nd[k]) / (n0 + 1e-12f)) * (s8[7 - k] - nd[k]) + 0.5f;
    red[w] = loss;
    red[4 + w] = (m == 0) ? 1.0f : 0.0f;
  }
  __syncthreads();
  if (threadIdx.x == 0) {
    pl[blockIdx.x] = red[0] + red[1] + red[2] + red[3];
    pc[blockIdx.x] = red[4] + red[5] + red[6] + red[7];
  }
}

// ---------------- misc: xent (blocks 0..1023) + side losses (1024..1535) ----------------
__global__ __launch_bounds__(256) void k_misc(const float* __restrict__ cls,
                                              const int* __restrict__ tgt,
                                              const float* __restrict__ l2,
                                              const float* __restrict__ l3,
                                              const float* __restrict__ l4,
                                              float* __restrict__ px,
                                              float* __restrict__ ps2,
                                              float* __restrict__ ps3) {
  const int lane = threadIdx.x & 63, wid = threadIdx.x >> 6;
  if (blockIdx.x < 1024) {
    // cross entropy: one wave per row
    const int row = blockIdx.x * 4 + wid;
    const float* x = cls + (size_t)row * NCLS;
    float mx = -1e30f;
    for (int c = lane; c < NCLS; c += 64) mx = fmaxf(mx, x[c]);
#pragma unroll
    for (int off = 32; off > 0; off >>= 1) mx = fmaxf(mx, __shfl_xor(mx, off, 64));
    float se = 0.0f;
    for (int c = lane; c < NCLS; c += 64) se += expf(x[c] - mx);
    se = wave_sum(se);
    __shared__ float redx[4];
    if (lane == 0) redx[wid] = logf(se) + mx - x[tgt[row]];
    __syncthreads();
    if (threadIdx.x == 0) px[blockIdx.x] = redx[0] + redx[1] + redx[2] + redx[3];
  } else {
    const int bid = blockIdx.x - 1024;   // 0..511
    float s2 = 0.0f, s3 = 0.0f;
    for (int i = bid * 256 + threadIdx.x; i < (NROWS * DSIDE / 4); i += 512 * 256) {
      const float4 a2 = ((const float4*)l2)[i];
      const float4 a3 = ((const float4*)l3)[i];
      const float4 a4 = ((const float4*)l4)[i];
      float dx = a4.x - a2.x, dy = a4.y - a2.y, dz = a4.z - a2.z, dw = a4.w - a2.w;
      s2 += dx * dx + dy * dy + dz * dz + dw * dw;
      dx = a4.x - a3.x; dy = a4.y - a3.y; dz = a4.z - a3.z; dw = a4.w - a3.w;
      s3 += dx * dx + dy * dy + dz * dz + dw * dw;
    }
    s2 = wave_sum(s2);
    s3 = wave_sum(s3);
    __shared__ float red[8];
    if (lane == 0) { red[wid] = s2; red[4 + wid] = s3; }
    __syncthreads();
    if (threadIdx.x == 0) {
      ps2[bid] = red[0] + red[1] + red[2] + red[3];
      ps3[bid] = red[4] + red[5] + red[6] + red[7];
    }
  }
}

// ---------------- finalize: sum partial arrays ----------------
__global__ __launch_bounds__(256) void k_fin(const float* __restrict__ pl,
                                             const float* __restrict__ pc,
                                             const float* __restrict__ px,
                                             const float* __restrict__ pa,
                                             const float* __restrict__ ps2,
                                             const float* __restrict__ ps3,
                                             float* __restrict__ out) {
  const int t = threadIdx.x;
  float s[6] = {0, 0, 0, 0, 0, 0};
  for (int i = t; i < 1024; i += 256) {
    s[0] += pl[i]; s[1] += pc[i]; s[2] += px[i]; s[3] += pa[i];
  }
  for (int i = t; i < 512; i += 256) {
    s[4] += ps2[i]; s[5] += ps3[i];
  }
  __shared__ float red[6][4];
  const int lane = t & 63, w = t >> 6;
#pragma unroll
  for (int j = 0; j < 6; ++j) {
    s[j] = wave_sum(s[j]);
    if (lane == 0) red[j][w] = s[j];
  }
  __syncthreads();
  if (t == 0) {
    const float rank_loss = (red[0][0] + red[0][1] + red[0][2] + red[0][3]) / (float)NROWS;
    const float prec      = (red[1][0] + red[1][1] + red[1][2] + red[1][3]) / (float)NROWS;
    const float xent      = (red[2][0] + red[2][1] + red[2][2] + red[2][3]) / (float)NROWS;
    const float acc       = (red[3][0] + red[3][1] + red[3][2] + red[3][3]) / (float)NROWS;
    const float side      = sqrtf(red[4][0] + red[4][1] + red[4][2] + red[4][3]) +
                            sqrtf(red[5][0] + red[5][1] + red[5][2] + red[5][3]);
    out[0] = rank_loss + xent + 0.1f * side;  // ALPHA=GAMMA=1, THETA=0.1
    out[1] = fmaxf(prec, acc);
  }
}

extern "C" void kernel_launch(void* const* d_in, const int* in_sizes, int n_in,
                              void* d_out, int out_size, void* d_ws, size_t ws_size,
                              hipStream_t stream) {
  (void)in_sizes; (void)n_in; (void)out_size; (void)ws_size;
  const float* cls = (const float*)d_in[0];
  const float* l2  = (const float*)d_in[1];
  const float* l3  = (const float*)d_in[2];
  const float* l4  = (const float*)d_in[3];
  const float* fea = (const float*)d_in[4];
  const int*   tgt = (const int*)d_in[5];
  float* out = (float*)d_out;

  // ws layout (floats): sq[4096] | Fhi (1M) | Flo (1M) | part (1M) | posw (32K)
  //                     | pa[1024] | pl[1024] | pc[1024] | px[1024] | ps2[512] | ps3[512]
  float* sq   = (float*)d_ws;
  unsigned short* Fhi = (unsigned short*)(sq + NROWS);
  unsigned short* Flo = Fhi + (size_t)NROWS * DFEA;
  float* part = (float*)(Flo + (size_t)NROWS * DFEA);
  float* posw = part + (size_t)NROWS * 256;
  float* pa   = posw + (size_t)NROWS * 8;
  float* pl   = pa + 1024;
  float* pc   = pl + 1024;
  float* px   = pc + 1024;
  float* ps2  = px + 1024;
  float* ps3  = ps2 + 512;

  k_prep<<<dim3(NROWS / 4), dim3(256), 0, stream>>>(fea, tgt, sq, pa, Fhi, Flo);
  k_gemm_mfma<<<dim3(528), dim3(256), 0, stream>>>(Fhi, Flo, sq, posw, part);
  k_rank<<<dim3(NROWS / 4), dim3(256), 0, stream>>>(part, posw, pl, pc);
  k_misc<<<dim3(1536), dim3(256), 0, stream>>>(cls, tgt, l2, l3, l4, px, ps2, ps3);
  k_fin<<<dim3(1), dim3(256), 0, stream>>>(pl, pc, px, pa, ps2, ps3, out);
}

// Round 9
// 180.860 us; speedup vs baseline: 1.5855x; 1.2309x over previous
//
#include <hip/hip_runtime.h>
#include <hip/hip_bf16.h>
#include <math.h>

// Problem constants (fixed-shape problem)
#define NROWS 4096
#define DFEA  512
#define NCLS  751
#define DSIDE 1024

typedef __attribute__((ext_vector_type(8))) short short8;
typedef __attribute__((ext_vector_type(4))) float f32x4;

__device__ __forceinline__ float wave_sum(float v) {
#pragma unroll
  for (int off = 32; off > 0; off >>= 1) v += __shfl_xor(v, off, 64);
  return v;
}

// async global->LDS, 16B per lane, wave-uniform LDS base + lane*16 (HW rule)
__device__ __forceinline__ void load_lds16(const void* g, void* l) {
  __builtin_amdgcn_global_load_lds((const __attribute__((address_space(1))) void*)g,
                                   (__attribute__((address_space(3))) void*)l, 16, 0, 0);
}

// branchless insert into ascending top-8 (drops the max)
__device__ __forceinline__ void ins8(float t8[8], float x) {
#pragma unroll
  for (int q = 0; q < 8; ++q) {
    const float lo = fminf(t8[q], x);
    x = fmaxf(t8[q], x);
    t8[q] = lo;
  }
}

#define CE(x, i, j) { const float ce_lo = fminf(x[i], x[j]); x[j] = fmaxf(x[i], x[j]); x[i] = ce_lo; }
#define SORT8_STAGE(c) \
  CE(c, 0, 4) CE(c, 1, 5) CE(c, 2, 6) CE(c, 3, 7) \
  CE(c, 0, 2) CE(c, 1, 3) CE(c, 4, 6) CE(c, 5, 7) \
  CE(c, 0, 1) CE(c, 2, 3) CE(c, 4, 5) CE(c, 6, 7)

// merge my ascending-8 with xor-partner's ascending-8, keep lowest 8 (sorted).
// masks <= 16 keep the two 32-lane halves of a wave independent.
__device__ __forceinline__ void merge_sorted8(float a[8], int mask) {
  float b[8];
#pragma unroll
  for (int i = 0; i < 8; ++i) b[i] = __shfl_xor(a[i], mask, 64);
  float c[8];
#pragma unroll
  for (int i = 0; i < 8; ++i) c[i] = fminf(a[i], b[7 - i]);  // lowest-8, bitonic
  SORT8_STAGE(c)
#pragma unroll
  for (int i = 0; i < 8; ++i) a[i] = c[i];
}

__device__ __forceinline__ unsigned short bf16bits(float v) {
  union { __hip_bfloat16 b; unsigned short u; } cv;
  cv.b = __float2bfloat16(v);
  return cv.u;
}

// ---------------- fused: row sum-of-squares + top1 accuracy + bf16 cast ----------------
__global__ __launch_bounds__(256) void k_prep(const float* __restrict__ fea,
                                              const int* __restrict__ tgt,
                                              float* __restrict__ sq,
                                              float* __restrict__ pa,
                                              unsigned short* __restrict__ Fhi) {
  const int lane = threadIdx.x & 63;
  const int wid  = threadIdx.x >> 6;
  const int row  = blockIdx.x * 4 + wid;
  const float4* xr = (const float4*)(fea + (size_t)row * DFEA);
  ushort4* hr = (ushort4*)(Fhi + (size_t)row * DFEA);
  float s = 0.0f, bv = -1e30f;
  int bi = 0;
#pragma unroll
  for (int q = 0; q < 2; ++q) {
    const int i4 = q * 64 + lane;
    const float4 v = xr[i4];
    s += v.x * v.x + v.y * v.y + v.z * v.z + v.w * v.w;
    const int c0 = i4 * 4;
    if (v.x > bv) { bv = v.x; bi = c0; }
    if (v.y > bv) { bv = v.y; bi = c0 + 1; }
    if (v.z > bv) { bv = v.z; bi = c0 + 2; }
    if (v.w > bv) { bv = v.w; bi = c0 + 3; }
    ushort4 h;
    h.x = bf16bits(v.x); h.y = bf16bits(v.y); h.z = bf16bits(v.z); h.w = bf16bits(v.w);
    hr[i4] = h;
  }
#pragma unroll
  for (int off = 32; off > 0; off >>= 1) {
    s += __shfl_xor(s, off, 64);
    const float ov = __shfl_xor(bv, off, 64);
    const int   oi = __shfl_xor(bi, off, 64);
    if (ov > bv || (ov == bv && oi < bi)) { bv = ov; bi = oi; }  // first-index on tie
  }
  __shared__ float red[4];
  if (lane == 0) {
    sq[row]  = s;
    red[wid] = (bi == tgt[row]) ? 1.0f : 0.0f;
  }
  __syncthreads();
  if (threadIdx.x == 0) pa[blockIdx.x] = red[0] + red[1] + red[2] + red[3];
}

// ---------------- mega kernel: GEMM+mining | xent | side losses by block role ----------------
// blocks [0,1024): distance GEMM (K=512, hi-only bf16) + per-row top-8 negative mining.
//   R3-proven structure: 128x128 tile, BK=64, 4 waves (2x2), per-wave 64x64 (acc[4][4]).
// blocks [1024,2048): cross entropy, 4 rows each.
// blocks [2048,2560): side losses, grid-stride.
__global__ __launch_bounds__(256) void k_mega(const unsigned short* __restrict__ Fhi,
                                              const float* __restrict__ sq,
                                              float* __restrict__ posw,
                                              float* __restrict__ part,
                                              const float* __restrict__ cls,
                                              const int* __restrict__ tgt,
                                              const float* __restrict__ l2,
                                              const float* __restrict__ l3,
                                              const float* __restrict__ l4,
                                              float* __restrict__ px,
                                              float* __restrict__ ps2,
                                              float* __restrict__ ps3) {
  const int bid = blockIdx.x;
  const int tid = threadIdx.x;
  const int lane = tid & 63, wid = tid >> 6;

  if (bid < 1024) {
    // ================= GEMM + mining role =================
    const int by = bid >> 5, bx = bid & 31;   // consecutive bids share by -> A-panel L2 reuse
    const int R0 = by * 128, C0 = bx * 128;
    const int wr = wid >> 1, wc = wid & 1;
    const int l15 = lane & 15, l4 = lane >> 4;

    __shared__ __attribute__((aligned(16))) char smem[33280];
    const __hip_bfloat16 (*As)[64] = (const __hip_bfloat16(*)[64])smem;           // 128x64, 16KB
    const __hip_bfloat16 (*Bs)[64] = (const __hip_bfloat16(*)[64])(smem + 16384); // 128x64, 16KB
    float (*dtile)[130] = (float(*)[130])smem;   // 64x130 f32 (33280B), aliased post-GEMM

    f32x4 acc[4][4];
#pragma unroll
    for (int m = 0; m < 4; ++m)
#pragma unroll
      for (int n = 0; n < 4; ++n) acc[m][n] = (f32x4){0.0f, 0.0f, 0.0f, 0.0f};

    for (int kt = 0; kt < 8; ++kt) {   // K = 512, hi-only
      const int ks = kt * 64;
      __syncthreads();  // previous iteration's ds_reads done before overwrite
#pragma unroll
      for (int i = 0; i < 4; ++i) {
        const int flat = i * 256 + tid;
        const int row = flat >> 3, c8 = flat & 7;
        load_lds16(Fhi + (size_t)(R0 + row) * DFEA + ks + c8 * 8,
                   smem + (i * 256 + wid * 64) * 16);
        load_lds16(Fhi + (size_t)(C0 + row) * DFEA + ks + c8 * 8,
                   smem + 16384 + (i * 256 + wid * 64) * 16);
      }
      __syncthreads();  // vmcnt(0) drain + barrier (compiler-inserted)
#pragma unroll
      for (int kk = 0; kk < 2; ++kk) {
        short8 af[4], bf[4];
#pragma unroll
        for (int m = 0; m < 4; ++m)
          af[m] = *(const short8*)&As[wr * 64 + m * 16 + l15][kk * 32 + l4 * 8];
#pragma unroll
        for (int n = 0; n < 4; ++n)
          bf[n] = *(const short8*)&Bs[wc * 64 + n * 16 + l15][kk * 32 + l4 * 8];
#pragma unroll
        for (int m = 0; m < 4; ++m)
#pragma unroll
          for (int n = 0; n < 4; ++n)
            acc[m][n] = __builtin_amdgcn_mfma_f32_16x16x32_bf16(af[m], bf[n], acc[m][n], 0, 0, 0);
      }
    }

    // epilogue: d2 = sq_i + sq_j - 2*dot; per-row top-8 negative mining (R3-proven)
    float sqi[4][4], sqj[4];
#pragma unroll
    for (int m = 0; m < 4; ++m)
#pragma unroll
      for (int r = 0; r < 4; ++r) sqi[m][r] = sq[R0 + wr * 64 + m * 16 + l4 * 4 + r];
#pragma unroll
    for (int n = 0; n < 4; ++n) sqj[n] = sq[C0 + wc * 64 + n * 16 + l15];

    const bool diag = (bx == by);

    for (int h = 0; h < 2; ++h) {  // two 64-row halves share the dtile
      __syncthreads();             // prior phase's LDS reads done
      if (wr == h) {
        // C/D layout (verified m89/m91): col = lane&15, row = (lane>>4)*4 + reg
#pragma unroll
        for (int m = 0; m < 4; ++m)
#pragma unroll
          for (int n = 0; n < 4; ++n)
#pragma unroll
            for (int r = 0; r < 4; ++r)
              dtile[m * 16 + l4 * 4 + r][wc * 64 + n * 16 + l15] =
                  sqi[m][r] + sqj[n] - 2.0f * acc[m][n][r];
      }
      __syncthreads();
      // row mining: 4 threads per row, 32 cols each (rotated to spread banks)
      const int r = tid >> 2, q = tid & 3;
      const int rg = R0 + h * 64 + r;
      float t8[8];
#pragma unroll
      for (int i = 0; i < 8; ++i) t8[i] = 1e30f;
      if (diag) {
        for (int s = 0; s < 32; ++s) {
          const int cl = q * 32 + ((s + 9 * q) & 31);
          const int cg = C0 + cl;
          const float v = dtile[r][cl];
          if (((rg ^ cg) >> 3) == 0) posw[(size_t)rg * 8 + (cg & 7)] = v;  // same identity
          else if (v < t8[7]) ins8(t8, v);
        }
      } else {
        for (int s = 0; s < 32; ++s) {
          const float v = dtile[r][q * 32 + ((s + 9 * q) & 31)];
          if (v < t8[7]) ins8(t8, v);
        }
      }
      merge_sorted8(t8, 1);
      merge_sorted8(t8, 2);
      if (q == 0) {
        const float4 o0 = {t8[0], t8[1], t8[2], t8[3]};
        const float4 o1 = {t8[4], t8[5], t8[6], t8[7]};
        *(float4*)&part[(size_t)rg * 256 + bx * 8] = o0;
        *(float4*)&part[(size_t)rg * 256 + bx * 8 + 4] = o1;
      }
    }
  } else if (bid < 2048) {
    // ================= cross entropy role (one wave per row) =================
    const int row = (bid - 1024) * 4 + wid;
    const float* x = cls + (size_t)row * NCLS;
    float mx = -1e30f;
    for (int c = lane; c < NCLS; c += 64) mx = fmaxf(mx, x[c]);
#pragma unroll
    for (int off = 32; off > 0; off >>= 1) mx = fmaxf(mx, __shfl_xor(mx, off, 64));
    float se = 0.0f;
    for (int c = lane; c < NCLS; c += 64) se += expf(x[c] - mx);
    se = wave_sum(se);
    __shared__ float redx[4];
    if (lane == 0) redx[wid] = logf(se) + mx - x[tgt[row]];
    __syncthreads();
    if (tid == 0) px[bid - 1024] = redx[0] + redx[1] + redx[2] + redx[3];
  } else {
    // ================= side-loss role (grid-stride) =================
    const int sb = bid - 2048;   // 0..511
    float s2 = 0.0f, s3 = 0.0f;
    for (int i = sb * 256 + tid; i < (NROWS * DSIDE / 4); i += 512 * 256) {
      const float4 a2 = ((const float4*)l2)[i];
      const float4 a3 = ((const float4*)l3)[i];
      const float4 a4 = ((const float4*)l4)[i];
      float dx = a4.x - a2.x, dy = a4.y - a2.y, dz = a4.z - a2.z, dw = a4.w - a2.w;
      s2 += dx * dx + dy * dy + dz * dz + dw * dw;
      dx = a4.x - a3.x; dy = a4.y - a3.y; dz = a4.z - a3.z; dw = a4.w - a3.w;
      s3 += dx * dx + dy * dy + dz * dz + dw * dw;
    }
    s2 = wave_sum(s2);
    s3 = wave_sum(s3);
    __shared__ float reds[8];
    if (lane == 0) { reds[wid] = s2; reds[4 + wid] = s3; }
    __syncthreads();
    if (tid == 0) {
      ps2[sb] = reds[0] + reds[1] + reds[2] + reds[3];
      ps3[sb] = reds[4] + reds[5] + reds[6] + reds[7];
    }
  }
}

// ---------------- rank loss: 2 rows per wave (masks<=16 keep 32-lane halves independent) ----------------
__global__ __launch_bounds__(256) void k_rank(const float* __restrict__ part,
                                              const float* __restrict__ posw,
                                              float* __restrict__ pl,
                                              float* __restrict__ pc) {
  const int lane = threadIdx.x & 63, w = threadIdx.x >> 6;
  const int half = lane >> 5, l32 = lane & 31;
  const int row = blockIdx.x * 8 + w * 2 + half;
  float a[8];
  const float4 v0 = *(const float4*)&part[(size_t)row * 256 + l32 * 8];
  const float4 v1 = *(const float4*)&part[(size_t)row * 256 + l32 * 8 + 4];
  a[0] = v0.x; a[1] = v0.y; a[2] = v0.z; a[3] = v0.w;
  a[4] = v1.x; a[5] = v1.y; a[6] = v1.z; a[7] = v1.w;
  merge_sorted8(a, 1);
  merge_sorted8(a, 2);
  merge_sorted8(a, 4);
  merge_sorted8(a, 8);
  merge_sorted8(a, 16);  // each 32-lane half holds its row's global top-8 (ascending d2)
  __shared__ float red[16];
  if (l32 == 0) {
    float nd[8];
#pragma unroll
    for (int i = 0; i < 8; ++i) nd[i] = sqrtf(fmaxf(a[i], 1e-12f));
    float s8[8];
#pragma unroll
    for (int i = 0; i < 8; ++i) s8[i] = 1e30f;
#pragma unroll
    for (int i = 0; i < 8; ++i)
      ins8(s8, sqrtf(fmaxf(posw[(size_t)row * 8 + i], 1e-12f)));  // positives ascending
    int ip = 0, in_ = 0;
#pragma unroll
    for (int s = 0; s < 8; ++s) {  // m = #negatives among 8 smallest of union
      const bool takeNeg = (in_ < 8) && (ip >= 8 || nd[in_] < s8[ip]);
      if (takeNeg) ++in_; else ++ip;
    }
    const int m = in_;
    float loss = 0.0f;
    const float n0 = nd[0];
    for (int k = 0; k < m; ++k)
      loss += (float)(m - k) * expf((n0 - nd[k]) / (n0 + 1e-12f)) * (s8[7 - k] - nd[k]) + 0.5f;
    red[w * 2 + half] = loss;
    red[8 + w * 2 + half] = (m == 0) ? 1.0f : 0.0f;
  }
  __syncthreads();
  if (threadIdx.x == 0) {
    float sl = 0.0f, sc = 0.0f;
#pragma unroll
    for (int i = 0; i < 8; ++i) { sl += red[i]; sc += red[8 + i]; }
    pl[blockIdx.x] = sl;
    pc[blockIdx.x] = sc;
  }
}

// ---------------- finalize: sum partial arrays ----------------
__global__ __launch_bounds__(256) void k_fin(const float* __restrict__ pl,
                                             const float* __restrict__ pc,
                                             const float* __restrict__ px,
                                             const float* __restrict__ pa,
                                             const float* __restrict__ ps2,
                                             const float* __restrict__ ps3,
                                             float* __restrict__ out) {
  const int t = threadIdx.x;
  float s[6] = {0, 0, 0, 0, 0, 0};
  for (int i = t; i < 1024; i += 256) { s[2] += px[i]; s[3] += pa[i]; }
  for (int i = t; i < 512; i += 256) {
    s[0] += pl[i]; s[1] += pc[i]; s[4] += ps2[i]; s[5] += ps3[i];
  }
  __shared__ float red[6][4];
  const int lane = t & 63, w = t >> 6;
#pragma unroll
  for (int j = 0; j < 6; ++j) {
    s[j] = wave_sum(s[j]);
    if (lane == 0) red[j][w] = s[j];
  }
  __syncthreads();
  if (t == 0) {
    const float rank_loss = (red[0][0] + red[0][1] + red[0][2] + red[0][3]) / (float)NROWS;
    const float prec      = (red[1][0] + red[1][1] + red[1][2] + red[1][3]) / (float)NROWS;
    const float xent      = (red[2][0] + red[2][1] + red[2][2] + red[2][3]) / (float)NROWS;
    const float acc       = (red[3][0] + red[3][1] + red[3][2] + red[3][3]) / (float)NROWS;
    const float side      = sqrtf(red[4][0] + red[4][1] + red[4][2] + red[4][3]) +
                            sqrtf(red[5][0] + red[5][1] + red[5][2] + red[5][3]);
    out[0] = rank_loss + xent + 0.1f * side;  // ALPHA=GAMMA=1, THETA=0.1
    out[1] = fmaxf(prec, acc);
  }
}

extern "C" void kernel_launch(void* const* d_in, const int* in_sizes, int n_in,
                              void* d_out, int out_size, void* d_ws, size_t ws_size,
                              hipStream_t stream) {
  (void)in_sizes; (void)n_in; (void)out_size; (void)ws_size;
  const float* cls = (const float*)d_in[0];
  const float* l2  = (const float*)d_in[1];
  const float* l3  = (const float*)d_in[2];
  const float* l4  = (const float*)d_in[3];
  const float* fea = (const float*)d_in[4];
  const int*   tgt = (const int*)d_in[5];
  float* out = (float*)d_out;

  // ws layout (floats): sq[4096] | Fhi (1M floats worth of ushort) | part (1M) | posw (32K)
  //                     | pa[1024] | pl[512] | pc[512] | px[1024] | ps2[512] | ps3[512]
  float* sq   = (float*)d_ws;
  unsigned short* Fhi = (unsigned short*)(sq + NROWS);
  float* part = (float*)(Fhi + (size_t)NROWS * DFEA);
  float* posw = part + (size_t)NROWS * 256;
  float* pa   = posw + (size_t)NROWS * 8;
  float* pl   = pa + 1024;
  float* pc   = pl + 512;
  float* px   = pc + 512;
  float* ps2  = px + 1024;
  float* ps3  = ps2 + 512;

  k_prep<<<dim3(NROWS / 4), dim3(256), 0, stream>>>(fea, tgt, sq, pa, Fhi);
  k_mega<<<dim3(2560), dim3(256), 0, stream>>>(Fhi, sq, posw, part, cls, tgt, l2, l3, l4,
                                               px, ps2, ps3);
  k_rank<<<dim3(NROWS / 8), dim3(256), 0, stream>>>(part, posw, pl, pc);
  k_fin<<<dim3(1), dim3(256), 0, stream>>>(pl, pc, px, pa, ps2, ps3, out);
}